// Round 19
// baseline (177.241 us; speedup 1.0000x reference)
//
#include <hip/hip_runtime.h>
#include <hip/hip_fp16.h>
#include <math.h>

#define NF 256
#define NH 128
#define NC 16
#define NB 391      // buckets of 128 nodes: 391*128 = 50048 >= 50000
#define NBLK 512    // binning blocks (passA/passB grid; scanR/scanC block dim)

typedef __attribute__((ext_vector_type(8))) short bf16x8;
typedef __attribute__((ext_vector_type(4))) float f32x4;

// ---- bf16 helper (W1T conversion only) ------------------------------------
__device__ __forceinline__ unsigned f2b(float f) {            // RNE to bf16 bits
    unsigned u = __float_as_uint(f);
    return (u + 0x7FFFu + ((u >> 16) & 1u)) >> 16;
}
__device__ __forceinline__ unsigned packt(float a, float b) { // truncate pair (MFMA inputs)
    return (__float_as_uint(a) >> 16) | (__float_as_uint(b) & 0xFFFF0000u);
}

// ---------------------------------------------------------------------------
// passA: per-block bucket histogram (LDS atomics only; coalesced row write).
__global__ void passA_kernel(const int* __restrict__ dst, int* __restrict__ hist, int E) {
    __shared__ int h[NB];
    for (int i = threadIdx.x; i < NB; i += 256) h[i] = 0;
    __syncthreads();
    int b = blockIdx.x;
    int e0 = (int)((long long)b * E / NBLK), e1 = (int)((long long)(b + 1) * E / NBLK);
    for (int e = e0 + (int)threadIdx.x; e < e1; e += 256)
        atomicAdd(&h[dst[e] >> 7], 1);
    __syncthreads();
    for (int i = threadIdx.x; i < NB; i += 256) hist[b * NB + i] = h[i];
}

// scanR: bucketsum[k] = sum over blocks of hist[b][k].  (NBLK threads)
__global__ void scanR_kernel(const int* __restrict__ hist, int* __restrict__ bsum) {
    __shared__ int sm[NBLK];
    int k = blockIdx.x, t = threadIdx.x;
    sm[t] = hist[t * NB + k];
    __syncthreads();
    for (int off = NBLK / 2; off > 0; off >>= 1) {
        if (t < off) sm[t] += sm[t + off];
        __syncthreads();
    }
    if (t == 0) bsum[k] = sm[0];
}

// scanB: dual exclusive scans -> ubase (unpadded, for ebuf) and pbase (padded,
// for colidx; per-bucket alloc = ((sum+7)&~7) + 904 covers 128 nodes x <=7 pad).
__global__ void scanB_kernel(const int* __restrict__ bsum, int* __restrict__ ubase,
                             int* __restrict__ pbase, int N, int E) {
    __shared__ int smu[512];
    __shared__ int smp[512];
    int t = threadIdx.x;
    int vu = (t < NB) ? bsum[t] : 0;
    int vp = (t < NB) ? (((vu + 7) & ~7) + 904) : 0;
    smu[t] = vu; smp[t] = vp;
    __syncthreads();
    for (int off = 1; off < 512; off <<= 1) {
        int uu = (t >= off) ? smu[t - off] : 0;
        int pp = (t >= off) ? smp[t - off] : 0;
        __syncthreads();
        smu[t] += uu; smp[t] += pp;
        __syncthreads();
    }
    if (t < NB) { ubase[t] = smu[t] - vu; pbase[t] = smp[t] - vp; }
    if (t == 0) ubase[NB] = E;
}

// scanC: per-bucket column exclusive scan across blocks + ubase
// (overwrites hist with each block's exact ebuf offset).  (NBLK threads)
__global__ void scanC_kernel(int* __restrict__ hist, const int* __restrict__ ubase) {
    __shared__ int sm[NBLK];
    int k = blockIdx.x, t = threadIdx.x;
    int v = hist[t * NB + k];
    sm[t] = v;
    __syncthreads();
    for (int off = 1; off < NBLK; off <<= 1) {
        int u = (t >= off) ? sm[t - off] : 0;
        __syncthreads();
        sm[t] += u;
        __syncthreads();
    }
    hist[t * NB + k] = ubase[k] + sm[t] - v;
}

// passB: binned scatter to bucket-sorted edge words (unpadded ebuf layout).
__global__ void passB_kernel(const int* __restrict__ src, const int* __restrict__ dst,
                             const int* __restrict__ hist, unsigned* __restrict__ ebuf,
                             int E) {
    __shared__ int cur[NB];
    int b = blockIdx.x;
    for (int i = threadIdx.x; i < NB; i += 256) cur[i] = hist[b * NB + i];
    __syncthreads();
    int e0 = (int)((long long)b * E / NBLK), e1 = (int)((long long)(b + 1) * E / NBLK);
    for (int e = e0 + (int)threadIdx.x; e < e1; e += 256) {
        int d = dst[e];
        int pos = atomicAdd(&cur[d >> 7], 1);
        ebuf[pos] = ((unsigned)d << 16) | (unsigned)src[e];
    }
}

// passC: one block per bucket: per-node histogram -> PADDED layout (each
// node's range 8-aligned, length (deg+7)&~7, pads = sentinel index N whose
// feature row is zero).  Writes rowptr (padded start), degs, dis, colidx.
__global__ void passC_kernel(const unsigned* __restrict__ ebuf, const int* __restrict__ ubase,
                             const int* __restrict__ pbase, int* __restrict__ rowptr,
                             int* __restrict__ degs, float* __restrict__ dis,
                             unsigned short* __restrict__ colidx, int N) {
    __shared__ int h[128];
    __shared__ int s2[128];
    __shared__ int curp[128];
    int k = blockIdx.x, t = threadIdx.x;
    if (t < 128) h[t] = 0;
    __syncthreads();
    int e0 = ubase[k], e1 = ubase[k + 1];
    for (int e = e0 + t; e < e1; e += 256)
        atomicAdd(&h[(ebuf[e] >> 16) & 127], 1);
    __syncthreads();
    int v = (t < 128) ? h[t] : 0;
    int pd = (v + 7) & ~7;
    if (t < 128) s2[t] = pd;
    __syncthreads();
    for (int off = 1; off < 128; off <<= 1) {
        int u = (t < 128 && t >= off) ? s2[t - off] : 0;
        __syncthreads();
        if (t < 128) s2[t] += u;
        __syncthreads();
    }
    if (t < 128) {
        int start = pbase[k] + s2[t] - pd;  // 8-aligned
        int node = k * 128 + t;
        if (node < N) {
            rowptr[node] = start;
            degs[node] = v;
            dis[node] = rsqrtf((float)(v + 1));
        }
        curp[t] = start;
    }
    __syncthreads();
    for (int e = e0 + t; e < e1; e += 256) {
        unsigned w = ebuf[e];
        int dl = (w >> 16) & 127;
        int pos = atomicAdd(&curp[dl], 1);
        colidx[pos] = (unsigned short)(w & 0xFFFFu);
    }
    __syncthreads();
    if (t < 128) {
        int endp = pbase[k] + s2[t];        // start + pd
        for (int q = curp[t]; q < endp; ++q) colidx[q] = (unsigned short)N;  // sentinel
    }
}

// ---------------------------------------------------------------------------
// W1T[n][k] = bf16(W1[k][n]) (64KB, L2-resident B operand).  Also zeroes the
// sentinel rows: h1T row N in each of the 4 slabs (16 u32) + h2sb row N (8).
__global__ void w1t_kernel(const float* __restrict__ W1, unsigned short* __restrict__ W1T,
                           unsigned* __restrict__ h1T, unsigned* __restrict__ h2sb, int N) {
    int idx = blockIdx.x * 256 + threadIdx.x;   // 128 blocks x 256 = 32768
    int n = idx >> 8, k = idx & 255;
    W1T[n * 256 + k] = (unsigned short)f2b(W1[(size_t)k * NH + n]);
    if (idx < 64) {
        int p = idx >> 4, j = idx & 15;
        h1T[(size_t)p * (N + 1) * 16 + (size_t)N * 16 + j] = 0u;
    } else if (idx < 72) {
        h2sb[(size_t)N * 8 + (idx - 64)] = 0u;
    }
}

// ---------------------------------------------------------------------------
// h1 = dis * (x @ W1) via MFMA bf16.  TLP fix (rounds 11-18: every gemm1
// variant flatlined at ~43us with Occupancy 14-22% -- the 782-block grid
// capped residency at 3 blocks/CU; latency could never be hidden).  Now:
// block = 16 rows x 128 cols, 4 waves each doing 16x32 -> grid 3125 blocks
// = 12.2 blocks/CU > VGPR-allowed residency; waves hide each other's
// latency.  All 4 waves read the same 16KB x-tile (L1 broadcast reuse).
// No LDS.  FP16 store, SLAB-MAJOR (slab p = wid), N+1 rows/slab.
__global__ __launch_bounds__(256) void gemm1_mfma_kernel(
    const float* __restrict__ x, const unsigned short* __restrict__ W1T,
    const float* __restrict__ dis, unsigned short* __restrict__ h1us, int N) {
    int tid = threadIdx.x;
    int wid = tid >> 6, lane = tid & 63;
    int lrow = lane & 15, lk = lane >> 4;      // A-frag: row=lane&15, k-chunk=lane>>4
    int rb = blockIdx.x * 16;
    int ra = rb + lrow;
    int rc = ra < N ? ra : N - 1;              // clamp (last block); extras discarded
    const float* xr = x + (size_t)rc * NF + lk * 8;

    bf16x8 a[8];
#pragma unroll
    for (int kk = 0; kk < 8; ++kk) {
        float4 lo = *reinterpret_cast<const float4*>(xr + kk * 32);
        float4 hi = *reinterpret_cast<const float4*>(xr + kk * 32 + 4);
        union { unsigned u[4]; bf16x8 v; } av;
        av.u[0] = packt(lo.x, lo.y);
        av.u[1] = packt(lo.z, lo.w);
        av.u[2] = packt(hi.x, hi.y);
        av.u[3] = packt(hi.z, hi.w);
        a[kk] = av.v;
    }

    f32x4 acc[2];
    acc[0] = (f32x4){0.f, 0.f, 0.f, 0.f};
    acc[1] = (f32x4){0.f, 0.f, 0.f, 0.f};

#pragma unroll
    for (int nt = 0; nt < 2; ++nt) {
        int n = wid * 32 + nt * 16 + lrow;     // B-frag: col=lane&15 within tile
        const unsigned short* wp = W1T + (size_t)n * 256 + lk * 8;
        bf16x8 b0 = *(const bf16x8*)(wp + 0 * 32);
        bf16x8 b1 = *(const bf16x8*)(wp + 1 * 32);
        bf16x8 b2 = *(const bf16x8*)(wp + 2 * 32);
        bf16x8 b3 = *(const bf16x8*)(wp + 3 * 32);
        bf16x8 b4 = *(const bf16x8*)(wp + 4 * 32);
        bf16x8 b5 = *(const bf16x8*)(wp + 5 * 32);
        bf16x8 b6 = *(const bf16x8*)(wp + 6 * 32);
        bf16x8 b7 = *(const bf16x8*)(wp + 7 * 32);
        acc[nt] = __builtin_amdgcn_mfma_f32_16x16x32_bf16(a[0], b0, acc[nt], 0, 0, 0);
        acc[nt] = __builtin_amdgcn_mfma_f32_16x16x32_bf16(a[1], b1, acc[nt], 0, 0, 0);
        acc[nt] = __builtin_amdgcn_mfma_f32_16x16x32_bf16(a[2], b2, acc[nt], 0, 0, 0);
        acc[nt] = __builtin_amdgcn_mfma_f32_16x16x32_bf16(a[3], b3, acc[nt], 0, 0, 0);
        acc[nt] = __builtin_amdgcn_mfma_f32_16x16x32_bf16(a[4], b4, acc[nt], 0, 0, 0);
        acc[nt] = __builtin_amdgcn_mfma_f32_16x16x32_bf16(a[5], b5, acc[nt], 0, 0, 0);
        acc[nt] = __builtin_amdgcn_mfma_f32_16x16x32_bf16(a[6], b6, acc[nt], 0, 0, 0);
        acc[nt] = __builtin_amdgcn_mfma_f32_16x16x32_bf16(a[7], b7, acc[nt], 0, 0, 0);
    }

    // C/D layout (verified m89): col = lane&15, row_in_tile = (lane>>4)*4 + r
    int crow0 = rb + lk * 4;
#pragma unroll
    for (int r = 0; r < 4; ++r) {
        int row = crow0 + r;
        if (row < N) {
            float dr = dis[row];
#pragma unroll
            for (int nt = 0; nt < 2; ++nt) {
                size_t ad = ((size_t)wid * (N + 1) + row) * 32 + (nt * 16 + lrow);
                __half hv = __float2half(acc[nt][r] * dr);
                h1us[ad] = __half_as_ushort(hv);
            }
        }
    }
}

// ---------------------------------------------------------------------------
// All 4 agg passes in ONE dispatch.  PADDED CSR -> pure unrolled blocks:
// prefetched uint4 idx + 8 gathers + 8 v_pk_add_f16.  Plain cached loads.
__global__ __launch_bounds__(256) void aggall_kernel(
    const int* __restrict__ rowptr, const int* __restrict__ degs,
    const unsigned short* __restrict__ colidx,
    const __half2* __restrict__ h1T, __half2* __restrict__ aggT, int N, int bps) {
    int p = blockIdx.x / bps;
    int i = (blockIdx.x - p * bps) * 16 + (threadIdx.x >> 4);
    if (i >= N) return;
    int l = threadIdx.x & 15;
    const __half2* slab = h1T + (size_t)p * (N + 1) * 16;
    __half2 acc = slab[(size_t)i * 16 + l];             // self-loop
    int e = rowptr[i];                                  // 8-aligned
    int cnt8 = (degs[i] + 7) >> 3;
    if (cnt8 > 0) {
        uint4 w = *reinterpret_cast<const uint4*>(colidx + e);
        for (int b = 1; b < cnt8; ++b) {
            uint4 wn = *reinterpret_cast<const uint4*>(colidx + e + 8 * b);  // prefetch
            int a0 = w.x & 0xFFFF, a1 = w.x >> 16;
            int a2 = w.y & 0xFFFF, a3 = w.y >> 16;
            int a4 = w.z & 0xFFFF, a5 = w.z >> 16;
            int a6 = w.w & 0xFFFF, a7 = w.w >> 16;
            __half2 v0 = slab[(size_t)a0 * 16 + l];
            __half2 v1 = slab[(size_t)a1 * 16 + l];
            __half2 v2 = slab[(size_t)a2 * 16 + l];
            __half2 v3 = slab[(size_t)a3 * 16 + l];
            __half2 v4 = slab[(size_t)a4 * 16 + l];
            __half2 v5 = slab[(size_t)a5 * 16 + l];
            __half2 v6 = slab[(size_t)a6 * 16 + l];
            __half2 v7 = slab[(size_t)a7 * 16 + l];
            __half2 s01 = __hadd2(v0, v1), s23 = __hadd2(v2, v3);
            __half2 s45 = __hadd2(v4, v5), s67 = __hadd2(v6, v7);
            acc = __hadd2(acc, __hadd2(__hadd2(s01, s23), __hadd2(s45, s67)));
            w = wn;
        }
        int a0 = w.x & 0xFFFF, a1 = w.x >> 16;
        int a2 = w.y & 0xFFFF, a3 = w.y >> 16;
        int a4 = w.z & 0xFFFF, a5 = w.z >> 16;
        int a6 = w.w & 0xFFFF, a7 = w.w >> 16;
        __half2 v0 = slab[(size_t)a0 * 16 + l];
        __half2 v1 = slab[(size_t)a1 * 16 + l];
        __half2 v2 = slab[(size_t)a2 * 16 + l];
        __half2 v3 = slab[(size_t)a3 * 16 + l];
        __half2 v4 = slab[(size_t)a4 * 16 + l];
        __half2 v5 = slab[(size_t)a5 * 16 + l];
        __half2 v6 = slab[(size_t)a6 * 16 + l];
        __half2 v7 = slab[(size_t)a7 * 16 + l];
        __half2 s01 = __hadd2(v0, v1), s23 = __hadd2(v2, v3);
        __half2 s45 = __hadd2(v4, v5), s67 = __hadd2(v6, v7);
        acc = __hadd2(acc, __hadd2(__hadd2(s01, s23), __hadd2(s45, s67)));
    }
    aggT[(size_t)p * N * 16 + (size_t)i * 16 + l] = acc;
}

// ---------------------------------------------------------------------------
// ReLU + bias + GEMM2 from aggT (fp16).  One wave per node (4 nodes/block).
__global__ __launch_bounds__(256) void relu_gemm2_kernel(
    const __half2* __restrict__ aggT, const float* __restrict__ dis,
    const float* __restrict__ b1, const float* __restrict__ W2,
    __half2* __restrict__ h2sb, int N) {
    __shared__ float sW2[NH * NC];   // 8 KB
    __shared__ float srow[4][NH];    // 2 KB
    int tid = threadIdx.x;
    for (int k = tid; k < NH * NC; k += 256) sW2[k] = W2[k];
    __syncthreads();

    int wid = tid >> 6, lane = tid & 63;
    int i = blockIdx.x * 4 + wid;
    if (i >= N) return;
    int p = lane >> 4, l16 = lane & 15;
    float2 f = __half22float2(aggT[((size_t)p * N + i) * 16 + l16]);
    float di = dis[i];
    int c0 = p * 32 + l16 * 2;
    srow[wid][c0]     = fmaxf(di * f.x + b1[c0], 0.f);
    srow[wid][c0 + 1] = fmaxf(di * f.y + b1[c0 + 1], 0.f);
    int j = lane & 15, q = lane >> 4;
    const float* rw = srow[wid];
    float pacc = 0.f;
#pragma unroll
    for (int cc = 0; cc < 32; ++cc) {
        int c = q * 32 + cc;
        pacc += rw[c] * sW2[c * NC + j];
    }
    pacc += __shfl_xor(pacc, 16, 64);
    pacc += __shfl_xor(pacc, 32, 64);
    float dp = di * pacc;
    float plo = __shfl(dp, (lane << 1) & 63, 64);
    float phi = __shfl(dp, ((lane << 1) | 1) & 63, 64);
    if (lane < 8) h2sb[(size_t)i * 8 + lane] = __floats2half2_rn(plo, phi);
}

// ---------------------------------------------------------------------------
// Layer 2 pull + bias + log_softmax.  8 lanes/node; padded CSR -> pure
// uint2-prefetched blocks of 4 (pads hit h2sb sentinel zero row N).
__global__ void layer2_kernel(const int* __restrict__ rowptr, const int* __restrict__ degs,
                              const unsigned short* __restrict__ colidx,
                              const __half2* __restrict__ h2sb, const float* __restrict__ dis,
                              const float* __restrict__ b2, float* __restrict__ out, int N) {
    int t = blockIdx.x * 256 + threadIdx.x;
    int i = t >> 3;
    if (i >= N) return;
    int j2 = t & 7;
    int e = rowptr[i];                                  // 8-aligned
    int cnt4 = (degs[i] + 3) >> 2;
    __half2 acc = h2sb[(size_t)i * 8 + j2];             // self-loop
    if (cnt4 > 0) {
        uint2 w = *reinterpret_cast<const uint2*>(colidx + e);
        for (int b = 1; b < cnt4; ++b) {
            uint2 wn = *reinterpret_cast<const uint2*>(colidx + e + 4 * b);  // prefetch
            int a0 = w.x & 0xFFFF, a1 = w.x >> 16;
            int a2 = w.y & 0xFFFF, a3 = w.y >> 16;
            __half2 g0 = h2sb[(size_t)a0 * 8 + j2];
            __half2 g1 = h2sb[(size_t)a1 * 8 + j2];
            __half2 g2 = h2sb[(size_t)a2 * 8 + j2];
            __half2 g3 = h2sb[(size_t)a3 * 8 + j2];
            acc = __hadd2(acc, __hadd2(__hadd2(g0, g1), __hadd2(g2, g3)));
            w = wn;
        }
        int a0 = w.x & 0xFFFF, a1 = w.x >> 16;
        int a2 = w.y & 0xFFFF, a3 = w.y >> 16;
        __half2 g0 = h2sb[(size_t)a0 * 8 + j2];
        __half2 g1 = h2sb[(size_t)a1 * 8 + j2];
        __half2 g2 = h2sb[(size_t)a2 * 8 + j2];
        __half2 g3 = h2sb[(size_t)a3 * 8 + j2];
        acc = __hadd2(acc, __hadd2(__hadd2(g0, g1), __hadd2(g2, g3)));
    }
    float2 f = __half22float2(acc);
    float di = dis[i];
    float l0 = di * f.x + b2[2 * j2];
    float l1 = di * f.y + b2[2 * j2 + 1];
    float m = fmaxf(l0, l1);
    m = fmaxf(m, __shfl_xor(m, 1, 64));
    m = fmaxf(m, __shfl_xor(m, 2, 64));
    m = fmaxf(m, __shfl_xor(m, 4, 64));
    float s = __expf(l0 - m) + __expf(l1 - m);
    s += __shfl_xor(s, 1, 64);
    s += __shfl_xor(s, 2, 64);
    s += __shfl_xor(s, 4, 64);
    float lse = m + __logf(s);
    float2 o = make_float2(l0 - lse, l1 - lse);
    *reinterpret_cast<float2*>(out + (size_t)i * NC + 2 * j2) = o;
}

// ---------------------------------------------------------------------------
extern "C" void kernel_launch(void* const* d_in, const int* in_sizes, int n_in,
                              void* d_out, int out_size, void* d_ws, size_t ws_size,
                              hipStream_t stream) {
    const float* x  = (const float*)d_in[0];
    const int*   ei = (const int*)d_in[1];
    const float* W1 = (const float*)d_in[2];
    const float* b1 = (const float*)d_in[3];
    const float* W2 = (const float*)d_in[4];
    const float* b2 = (const float*)d_in[5];
    float* out = (float*)d_out;

    const int N = in_sizes[0] / NF;   // 50000
    const int E = in_sizes[1] / 2;    // 1600000
    const int* src = ei;
    const int* dst = ei + E;

    // workspace layout (~39 MB); every consumed cell rewritten per call.
    __half2*        h1T    = (__half2*)d_ws;                   // 4*(N+1)*16 u32 (sentinel rows)
    __half2*        aggT   = h1T + (size_t)4 * (N + 1) * 16;   // 4*N*16 u32
    __half2*        h2sb   = aggT + (size_t)4 * N * 16;        // (N+1)*8 u32 (sentinel row)
    float*          dis    = (float*)(h2sb + (size_t)(N + 1) * 8); // N
    int*            degs   = (int*)(dis + N);                  // N
    int*            rowptr = degs + N;                         // N
    int*            hist   = rowptr + N;                       // NBLK*NB (0.8 MB)
    int*            bsum   = hist + NBLK * NB;                 // NB
    int*            ubase  = bsum + NB;                        // NB+1
    int*            pbase  = ubase + NB + 1;                   // NB
    unsigned*       ebuf   = (unsigned*)(pbase + NB + 1);      // E u32 (6.4 MB)
    unsigned short* colidx = (unsigned short*)(ebuf + E);      // E+360000 u16 (~3.9 MB)
    // W1T (64KB) overlays ebuf: ebuf is dead after passC, W1T written after.
    unsigned short* W1T    = (unsigned short*)ebuf;

    passA_kernel<<<NBLK, 256, 0, stream>>>(dst, hist, E);
    scanR_kernel<<<NB, NBLK, 0, stream>>>(hist, bsum);
    scanB_kernel<<<1, 512, 0, stream>>>(bsum, ubase, pbase, N, E);
    scanC_kernel<<<NB, NBLK, 0, stream>>>(hist, ubase);
    passB_kernel<<<NBLK, 256, 0, stream>>>(src, dst, hist, ebuf, E);
    passC_kernel<<<NB, 256, 0, stream>>>(ebuf, ubase, pbase, rowptr, degs, dis, colidx, N);

    w1t_kernel<<<128, 256, 0, stream>>>(W1, W1T, (unsigned*)h1T, (unsigned*)h2sb, N);

    gemm1_mfma_kernel<<<(N + 15) / 16, 256, 0, stream>>>(x, W1T, dis,
                                                         (unsigned short*)h1T, N);

    const int bps = (N + 15) / 16;   // blocks per slab
    aggall_kernel<<<4 * bps, 256, 0, stream>>>(rowptr, degs, colidx, h1T, aggT, N, bps);

    relu_gemm2_kernel<<<(N + 3) / 4, 256, 0, stream>>>(aggT, dis, b1, W2, h2sb, N);

    layer2_kernel<<<((size_t)N * 8 + 255) / 256, 256, 0, stream>>>(rowptr, degs, colidx, h2sb, dis, b2, out, N);
}

// Round 20
// 163.611 us; speedup vs baseline: 1.0833x; 1.0833x over previous
//
#include <hip/hip_runtime.h>
#include <hip/hip_fp16.h>
#include <math.h>

#define NF 256
#define NH 128
#define NC 16
#define NB 391      // buckets of 128 nodes: 391*128 = 50048 >= 50000
#define NBLK 512    // binning blocks (passA/passB grid; scanR/scanC block dim)

typedef __attribute__((ext_vector_type(8))) short bf16x8;
typedef __attribute__((ext_vector_type(4))) float f32x4;

// ---- bf16 helper (W1T conversion only) ------------------------------------
__device__ __forceinline__ unsigned f2b(float f) {            // RNE to bf16 bits
    unsigned u = __float_as_uint(f);
    return (u + 0x7FFFu + ((u >> 16) & 1u)) >> 16;
}
__device__ __forceinline__ unsigned packt(float a, float b) { // truncate pair (MFMA inputs)
    return (__float_as_uint(a) >> 16) | (__float_as_uint(b) & 0xFFFF0000u);
}

// ---------------------------------------------------------------------------
// passA: per-block bucket histogram (LDS atomics only; coalesced row write).
__global__ void passA_kernel(const int* __restrict__ dst, int* __restrict__ hist, int E) {
    __shared__ int h[NB];
    for (int i = threadIdx.x; i < NB; i += 256) h[i] = 0;
    __syncthreads();
    int b = blockIdx.x;
    int e0 = (int)((long long)b * E / NBLK), e1 = (int)((long long)(b + 1) * E / NBLK);
    for (int e = e0 + (int)threadIdx.x; e < e1; e += 256)
        atomicAdd(&h[dst[e] >> 7], 1);
    __syncthreads();
    for (int i = threadIdx.x; i < NB; i += 256) hist[b * NB + i] = h[i];
}

// scanR: bucketsum[k] = sum over blocks of hist[b][k].  (NBLK threads)
__global__ void scanR_kernel(const int* __restrict__ hist, int* __restrict__ bsum) {
    __shared__ int sm[NBLK];
    int k = blockIdx.x, t = threadIdx.x;
    sm[t] = hist[t * NB + k];
    __syncthreads();
    for (int off = NBLK / 2; off > 0; off >>= 1) {
        if (t < off) sm[t] += sm[t + off];
        __syncthreads();
    }
    if (t == 0) bsum[k] = sm[0];
}

// scanB: dual exclusive scans -> ubase (unpadded, for ebuf) and pbase (padded,
// for colidx; per-bucket alloc = ((sum+7)&~7) + 904 covers 128 nodes x <=7 pad).
__global__ void scanB_kernel(const int* __restrict__ bsum, int* __restrict__ ubase,
                             int* __restrict__ pbase, int N, int E) {
    __shared__ int smu[512];
    __shared__ int smp[512];
    int t = threadIdx.x;
    int vu = (t < NB) ? bsum[t] : 0;
    int vp = (t < NB) ? (((vu + 7) & ~7) + 904) : 0;
    smu[t] = vu; smp[t] = vp;
    __syncthreads();
    for (int off = 1; off < 512; off <<= 1) {
        int uu = (t >= off) ? smu[t - off] : 0;
        int pp = (t >= off) ? smp[t - off] : 0;
        __syncthreads();
        smu[t] += uu; smp[t] += pp;
        __syncthreads();
    }
    if (t < NB) { ubase[t] = smu[t] - vu; pbase[t] = smp[t] - vp; }
    if (t == 0) ubase[NB] = E;
}

// scanC: per-bucket column exclusive scan across blocks + ubase
// (overwrites hist with each block's exact ebuf offset).  (NBLK threads)
__global__ void scanC_kernel(int* __restrict__ hist, const int* __restrict__ ubase) {
    __shared__ int sm[NBLK];
    int k = blockIdx.x, t = threadIdx.x;
    int v = hist[t * NB + k];
    sm[t] = v;
    __syncthreads();
    for (int off = 1; off < NBLK; off <<= 1) {
        int u = (t >= off) ? sm[t - off] : 0;
        __syncthreads();
        sm[t] += u;
        __syncthreads();
    }
    hist[t * NB + k] = ubase[k] + sm[t] - v;
}

// passB: binned scatter to bucket-sorted edge words (unpadded ebuf layout).
__global__ void passB_kernel(const int* __restrict__ src, const int* __restrict__ dst,
                             const int* __restrict__ hist, unsigned* __restrict__ ebuf,
                             int E) {
    __shared__ int cur[NB];
    int b = blockIdx.x;
    for (int i = threadIdx.x; i < NB; i += 256) cur[i] = hist[b * NB + i];
    __syncthreads();
    int e0 = (int)((long long)b * E / NBLK), e1 = (int)((long long)(b + 1) * E / NBLK);
    for (int e = e0 + (int)threadIdx.x; e < e1; e += 256) {
        int d = dst[e];
        int pos = atomicAdd(&cur[d >> 7], 1);
        ebuf[pos] = ((unsigned)d << 16) | (unsigned)src[e];
    }
}

// passC: one block per bucket: per-node histogram -> PADDED layout (each
// node's range 8-aligned, length (deg+7)&~7, pads = sentinel index N whose
// feature row is zero).  Writes rowptr (padded start), degs, dis, colidx.
__global__ void passC_kernel(const unsigned* __restrict__ ebuf, const int* __restrict__ ubase,
                             const int* __restrict__ pbase, int* __restrict__ rowptr,
                             int* __restrict__ degs, float* __restrict__ dis,
                             unsigned short* __restrict__ colidx, int N) {
    __shared__ int h[128];
    __shared__ int s2[128];
    __shared__ int curp[128];
    int k = blockIdx.x, t = threadIdx.x;
    if (t < 128) h[t] = 0;
    __syncthreads();
    int e0 = ubase[k], e1 = ubase[k + 1];
    for (int e = e0 + t; e < e1; e += 256)
        atomicAdd(&h[(ebuf[e] >> 16) & 127], 1);
    __syncthreads();
    int v = (t < 128) ? h[t] : 0;
    int pd = (v + 7) & ~7;
    if (t < 128) s2[t] = pd;
    __syncthreads();
    for (int off = 1; off < 128; off <<= 1) {
        int u = (t < 128 && t >= off) ? s2[t - off] : 0;
        __syncthreads();
        if (t < 128) s2[t] += u;
        __syncthreads();
    }
    if (t < 128) {
        int start = pbase[k] + s2[t] - pd;  // 8-aligned
        int node = k * 128 + t;
        if (node < N) {
            rowptr[node] = start;
            degs[node] = v;
            dis[node] = rsqrtf((float)(v + 1));
        }
        curp[t] = start;
    }
    __syncthreads();
    for (int e = e0 + t; e < e1; e += 256) {
        unsigned w = ebuf[e];
        int dl = (w >> 16) & 127;
        int pos = atomicAdd(&curp[dl], 1);
        colidx[pos] = (unsigned short)(w & 0xFFFFu);
    }
    __syncthreads();
    if (t < 128) {
        int endp = pbase[k] + s2[t];        // start + pd
        for (int q = curp[t]; q < endp; ++q) colidx[q] = (unsigned short)N;  // sentinel
    }
}

// ---------------------------------------------------------------------------
// W1T[n][k] = bf16(W1[k][n]) (64KB, L2-resident B operand).  Also zeroes the
// sentinel rows: h1T row N in each of the 4 slabs (16 u32) + h2sb row N (8).
__global__ void w1t_kernel(const float* __restrict__ W1, unsigned short* __restrict__ W1T,
                           unsigned* __restrict__ h1T, unsigned* __restrict__ h2sb, int N) {
    int idx = blockIdx.x * 256 + threadIdx.x;   // 128 blocks x 256 = 32768
    int n = idx >> 8, k = idx & 255;
    W1T[n * 256 + k] = (unsigned short)f2b(W1[(size_t)k * NH + n]);
    if (idx < 64) {
        int p = idx >> 4, j = idx & 15;
        h1T[(size_t)p * (N + 1) * 16 + (size_t)N * 16 + j] = 0u;
    } else if (idx < 72) {
        h2sb[(size_t)N * 8 + (idx - 64)] = 0u;
    }
}

// ---------------------------------------------------------------------------
// h1 = dis * (x @ W1) via MFMA bf16.  MLP fix (round 19 measured: VGPR-based
// x-loads cap HBM BW at ~460 GB/s = 2 loads in flight/wave x 900cy latency;
// FETCH 25.5MB / 460GB/s = the whole 55us).  global_load_lds carries MLP
// WITHOUT VGPRs: each wave issues 8 async 1KB stages back-to-back; 32KB
// tile -> 5 blocks/CU resident -> ~160KB/CU in flight -> BW no longer
// MLP-capped.  XOR swizzle (row&7)<<1 on SOURCE units + same XOR on LDS
// read (rule #21 involution) -> A-frag ds_read ~2-way conflicts (free).
// Waves: rt=wid&1 (16 rows), nh=wid>>1 (64 cols = 4 n-tiles).
// FP16 store, SLAB-MAJOR, N+1 rows/slab (row N = sentinel zero row).
__global__ __launch_bounds__(256) void gemm1_mfma_kernel(
    const float* __restrict__ x, const unsigned short* __restrict__ W1T,
    const float* __restrict__ dis, unsigned short* __restrict__ h1us, int N) {
    __shared__ char sx[32768];                 // [32 rows][64 units of 16B]
    int tid = threadIdx.x;
    int wid = tid >> 6, lane = tid & 63;

    // stage 32 rows x 1KB: iter it -> row lr = it*4+wid; LDS linear,
    // source unit = lane ^ ((lr&7)<<1).
    for (int it = 0; it < 8; ++it) {
        int lr = it * 4 + wid;
        int grow = blockIdx.x * 32 + lr;
        if (grow >= N) grow = N - 1;           // wave-uniform clamp (extras discarded)
        int fsw = (lr & 7) << 1;
        const char* gp = (const char*)x + (size_t)grow * 1024 + ((lane ^ fsw) << 4);
        __builtin_amdgcn_global_load_lds(gp, sx + lr * 1024 + lane * 16, 16, 0, 0);
    }
    __syncthreads();

    int lrow = lane & 15, lk = lane >> 4;      // A-frag: row=lane&15, k-chunk=lane>>4
    int rt = wid & 1, nh = wid >> 1;
    int lr = rt * 16 + lrow;                   // local row this lane reads
    int fr = (lr & 7) << 1;                    // read-side XOR (lr&7 == lrow&7)
    const float4* lds4 = (const float4*)sx;

    // build A fragments from LDS (two b128 per kk, pack to bf16)
    bf16x8 a[8];
#pragma unroll
    for (int kk = 0; kk < 8; ++kk) {
        int v = (kk * 8 + lk * 2) ^ fr;        // fr even -> pair stays contiguous
        float4 lo = lds4[lr * 64 + v];
        float4 hi = lds4[lr * 64 + v + 1];
        union { unsigned u[4]; bf16x8 vv; } av;
        av.u[0] = packt(lo.x, lo.y);
        av.u[1] = packt(lo.z, lo.w);
        av.u[2] = packt(hi.x, hi.y);
        av.u[3] = packt(hi.z, hi.w);
        a[kk] = av.vv;
    }

    f32x4 acc[4];
#pragma unroll
    for (int t = 0; t < 4; ++t) acc[t] = (f32x4){0.f, 0.f, 0.f, 0.f};

#pragma unroll
    for (int nt = 0; nt < 4; ++nt) {
        int n = nh * 64 + nt * 16 + lrow;      // B-frag: col=lane&15, k-chunk=lane>>4
        const unsigned short* wp = W1T + (size_t)n * 256 + lk * 8;
        bf16x8 b0 = *(const bf16x8*)(wp + 0 * 32);
        bf16x8 b1 = *(const bf16x8*)(wp + 1 * 32);
        bf16x8 b2 = *(const bf16x8*)(wp + 2 * 32);
        bf16x8 b3 = *(const bf16x8*)(wp + 3 * 32);
        bf16x8 b4 = *(const bf16x8*)(wp + 4 * 32);
        bf16x8 b5 = *(const bf16x8*)(wp + 5 * 32);
        bf16x8 b6 = *(const bf16x8*)(wp + 6 * 32);
        bf16x8 b7 = *(const bf16x8*)(wp + 7 * 32);
        acc[nt] = __builtin_amdgcn_mfma_f32_16x16x32_bf16(a[0], b0, acc[nt], 0, 0, 0);
        acc[nt] = __builtin_amdgcn_mfma_f32_16x16x32_bf16(a[1], b1, acc[nt], 0, 0, 0);
        acc[nt] = __builtin_amdgcn_mfma_f32_16x16x32_bf16(a[2], b2, acc[nt], 0, 0, 0);
        acc[nt] = __builtin_amdgcn_mfma_f32_16x16x32_bf16(a[3], b3, acc[nt], 0, 0, 0);
        acc[nt] = __builtin_amdgcn_mfma_f32_16x16x32_bf16(a[4], b4, acc[nt], 0, 0, 0);
        acc[nt] = __builtin_amdgcn_mfma_f32_16x16x32_bf16(a[5], b5, acc[nt], 0, 0, 0);
        acc[nt] = __builtin_amdgcn_mfma_f32_16x16x32_bf16(a[6], b6, acc[nt], 0, 0, 0);
        acc[nt] = __builtin_amdgcn_mfma_f32_16x16x32_bf16(a[7], b7, acc[nt], 0, 0, 0);
    }

    // C/D layout (verified m89): col = lane&15, row_in_tile = (lane>>4)*4 + r
    int rb = blockIdx.x * 32;
    int crow0 = rb + rt * 16 + lk * 4;
#pragma unroll
    for (int r = 0; r < 4; ++r) {
        int row = crow0 + r;
        if (row < N) {
            float dr = dis[row];
#pragma unroll
            for (int nt = 0; nt < 4; ++nt) {
                int p = nh * 2 + (nt >> 1);            // slab index
                size_t ad = ((size_t)p * (N + 1) + row) * 32 + ((nt & 1) * 16 + lrow);
                __half hv = __float2half(acc[nt][r] * dr);
                h1us[ad] = __half_as_ushort(hv);
            }
        }
    }
}

// ---------------------------------------------------------------------------
// All 4 agg passes in ONE dispatch.  PADDED CSR -> pure unrolled blocks:
// prefetched uint4 idx + 8 gathers + 8 v_pk_add_f16.  Plain cached loads.
__global__ __launch_bounds__(256) void aggall_kernel(
    const int* __restrict__ rowptr, const int* __restrict__ degs,
    const unsigned short* __restrict__ colidx,
    const __half2* __restrict__ h1T, __half2* __restrict__ aggT, int N, int bps) {
    int p = blockIdx.x / bps;
    int i = (blockIdx.x - p * bps) * 16 + (threadIdx.x >> 4);
    if (i >= N) return;
    int l = threadIdx.x & 15;
    const __half2* slab = h1T + (size_t)p * (N + 1) * 16;
    __half2 acc = slab[(size_t)i * 16 + l];             // self-loop
    int e = rowptr[i];                                  // 8-aligned
    int cnt8 = (degs[i] + 7) >> 3;
    if (cnt8 > 0) {
        uint4 w = *reinterpret_cast<const uint4*>(colidx + e);
        for (int b = 1; b < cnt8; ++b) {
            uint4 wn = *reinterpret_cast<const uint4*>(colidx + e + 8 * b);  // prefetch
            int a0 = w.x & 0xFFFF, a1 = w.x >> 16;
            int a2 = w.y & 0xFFFF, a3 = w.y >> 16;
            int a4 = w.z & 0xFFFF, a5 = w.z >> 16;
            int a6 = w.w & 0xFFFF, a7 = w.w >> 16;
            __half2 v0 = slab[(size_t)a0 * 16 + l];
            __half2 v1 = slab[(size_t)a1 * 16 + l];
            __half2 v2 = slab[(size_t)a2 * 16 + l];
            __half2 v3 = slab[(size_t)a3 * 16 + l];
            __half2 v4 = slab[(size_t)a4 * 16 + l];
            __half2 v5 = slab[(size_t)a5 * 16 + l];
            __half2 v6 = slab[(size_t)a6 * 16 + l];
            __half2 v7 = slab[(size_t)a7 * 16 + l];
            __half2 s01 = __hadd2(v0, v1), s23 = __hadd2(v2, v3);
            __half2 s45 = __hadd2(v4, v5), s67 = __hadd2(v6, v7);
            acc = __hadd2(acc, __hadd2(__hadd2(s01, s23), __hadd2(s45, s67)));
            w = wn;
        }
        int a0 = w.x & 0xFFFF, a1 = w.x >> 16;
        int a2 = w.y & 0xFFFF, a3 = w.y >> 16;
        int a4 = w.z & 0xFFFF, a5 = w.z >> 16;
        int a6 = w.w & 0xFFFF, a7 = w.w >> 16;
        __half2 v0 = slab[(size_t)a0 * 16 + l];
        __half2 v1 = slab[(size_t)a1 * 16 + l];
        __half2 v2 = slab[(size_t)a2 * 16 + l];
        __half2 v3 = slab[(size_t)a3 * 16 + l];
        __half2 v4 = slab[(size_t)a4 * 16 + l];
        __half2 v5 = slab[(size_t)a5 * 16 + l];
        __half2 v6 = slab[(size_t)a6 * 16 + l];
        __half2 v7 = slab[(size_t)a7 * 16 + l];
        __half2 s01 = __hadd2(v0, v1), s23 = __hadd2(v2, v3);
        __half2 s45 = __hadd2(v4, v5), s67 = __hadd2(v6, v7);
        acc = __hadd2(acc, __hadd2(__hadd2(s01, s23), __hadd2(s45, s67)));
    }
    aggT[(size_t)p * N * 16 + (size_t)i * 16 + l] = acc;
}

// ---------------------------------------------------------------------------
// ReLU + bias + GEMM2 from aggT (fp16).  One wave per node (4 nodes/block).
__global__ __launch_bounds__(256) void relu_gemm2_kernel(
    const __half2* __restrict__ aggT, const float* __restrict__ dis,
    const float* __restrict__ b1, const float* __restrict__ W2,
    __half2* __restrict__ h2sb, int N) {
    __shared__ float sW2[NH * NC];   // 8 KB
    __shared__ float srow[4][NH];    // 2 KB
    int tid = threadIdx.x;
    for (int k = tid; k < NH * NC; k += 256) sW2[k] = W2[k];
    __syncthreads();

    int wid = tid >> 6, lane = tid & 63;
    int i = blockIdx.x * 4 + wid;
    if (i >= N) return;
    int p = lane >> 4, l16 = lane & 15;
    float2 f = __half22float2(aggT[((size_t)p * N + i) * 16 + l16]);
    float di = dis[i];
    int c0 = p * 32 + l16 * 2;
    srow[wid][c0]     = fmaxf(di * f.x + b1[c0], 0.f);
    srow[wid][c0 + 1] = fmaxf(di * f.y + b1[c0 + 1], 0.f);
    int j = lane & 15, q = lane >> 4;
    const float* rw = srow[wid];
    float pacc = 0.f;
#pragma unroll
    for (int cc = 0; cc < 32; ++cc) {
        int c = q * 32 + cc;
        pacc += rw[c] * sW2[c * NC + j];
    }
    pacc += __shfl_xor(pacc, 16, 64);
    pacc += __shfl_xor(pacc, 32, 64);
    float dp = di * pacc;
    float plo = __shfl(dp, (lane << 1) & 63, 64);
    float phi = __shfl(dp, ((lane << 1) | 1) & 63, 64);
    if (lane < 8) h2sb[(size_t)i * 8 + lane] = __floats2half2_rn(plo, phi);
}

// ---------------------------------------------------------------------------
// Layer 2 pull + bias + log_softmax.  8 lanes/node; padded CSR -> pure
// uint2-prefetched blocks of 4 (pads hit h2sb sentinel zero row N).
__global__ void layer2_kernel(const int* __restrict__ rowptr, const int* __restrict__ degs,
                              const unsigned short* __restrict__ colidx,
                              const __half2* __restrict__ h2sb, const float* __restrict__ dis,
                              const float* __restrict__ b2, float* __restrict__ out, int N) {
    int t = blockIdx.x * 256 + threadIdx.x;
    int i = t >> 3;
    if (i >= N) return;
    int j2 = t & 7;
    int e = rowptr[i];                                  // 8-aligned
    int cnt4 = (degs[i] + 3) >> 2;
    __half2 acc = h2sb[(size_t)i * 8 + j2];             // self-loop
    if (cnt4 > 0) {
        uint2 w = *reinterpret_cast<const uint2*>(colidx + e);
        for (int b = 1; b < cnt4; ++b) {
            uint2 wn = *reinterpret_cast<const uint2*>(colidx + e + 4 * b);  // prefetch
            int a0 = w.x & 0xFFFF, a1 = w.x >> 16;
            int a2 = w.y & 0xFFFF, a3 = w.y >> 16;
            __half2 g0 = h2sb[(size_t)a0 * 8 + j2];
            __half2 g1 = h2sb[(size_t)a1 * 8 + j2];
            __half2 g2 = h2sb[(size_t)a2 * 8 + j2];
            __half2 g3 = h2sb[(size_t)a3 * 8 + j2];
            acc = __hadd2(acc, __hadd2(__hadd2(g0, g1), __hadd2(g2, g3)));
            w = wn;
        }
        int a0 = w.x & 0xFFFF, a1 = w.x >> 16;
        int a2 = w.y & 0xFFFF, a3 = w.y >> 16;
        __half2 g0 = h2sb[(size_t)a0 * 8 + j2];
        __half2 g1 = h2sb[(size_t)a1 * 8 + j2];
        __half2 g2 = h2sb[(size_t)a2 * 8 + j2];
        __half2 g3 = h2sb[(size_t)a3 * 8 + j2];
        acc = __hadd2(acc, __hadd2(__hadd2(g0, g1), __hadd2(g2, g3)));
    }
    float2 f = __half22float2(acc);
    float di = dis[i];
    float l0 = di * f.x + b2[2 * j2];
    float l1 = di * f.y + b2[2 * j2 + 1];
    float m = fmaxf(l0, l1);
    m = fmaxf(m, __shfl_xor(m, 1, 64));
    m = fmaxf(m, __shfl_xor(m, 2, 64));
    m = fmaxf(m, __shfl_xor(m, 4, 64));
    float s = __expf(l0 - m) + __expf(l1 - m);
    s += __shfl_xor(s, 1, 64);
    s += __shfl_xor(s, 2, 64);
    s += __shfl_xor(s, 4, 64);
    float lse = m + __logf(s);
    float2 o = make_float2(l0 - lse, l1 - lse);
    *reinterpret_cast<float2*>(out + (size_t)i * NC + 2 * j2) = o;
}

// ---------------------------------------------------------------------------
extern "C" void kernel_launch(void* const* d_in, const int* in_sizes, int n_in,
                              void* d_out, int out_size, void* d_ws, size_t ws_size,
                              hipStream_t stream) {
    const float* x  = (const float*)d_in[0];
    const int*   ei = (const int*)d_in[1];
    const float* W1 = (const float*)d_in[2];
    const float* b1 = (const float*)d_in[3];
    const float* W2 = (const float*)d_in[4];
    const float* b2 = (const float*)d_in[5];
    float* out = (float*)d_out;

    const int N = in_sizes[0] / NF;   // 50000
    const int E = in_sizes[1] / 2;    // 1600000
    const int* src = ei;
    const int* dst = ei + E;

    // workspace layout (~39 MB); every consumed cell rewritten per call.
    __half2*        h1T    = (__half2*)d_ws;                   // 4*(N+1)*16 u32 (sentinel rows)
    __half2*        aggT   = h1T + (size_t)4 * (N + 1) * 16;   // 4*N*16 u32
    __half2*        h2sb   = aggT + (size_t)4 * N * 16;        // (N+1)*8 u32 (sentinel row)
    float*          dis    = (float*)(h2sb + (size_t)(N + 1) * 8); // N
    int*            degs   = (int*)(dis + N);                  // N
    int*            rowptr = degs + N;                         // N
    int*            hist   = rowptr + N;                       // NBLK*NB (0.8 MB)
    int*            bsum   = hist + NBLK * NB;                 // NB
    int*            ubase  = bsum + NB;                        // NB+1
    int*            pbase  = ubase + NB + 1;                   // NB
    unsigned*       ebuf   = (unsigned*)(pbase + NB + 1);      // E u32 (6.4 MB)
    unsigned short* colidx = (unsigned short*)(ebuf + E);      // E+360000 u16 (~3.9 MB)
    // W1T (64KB) overlays ebuf: ebuf is dead after passC, W1T written after.
    unsigned short* W1T    = (unsigned short*)ebuf;

    passA_kernel<<<NBLK, 256, 0, stream>>>(dst, hist, E);
    scanR_kernel<<<NB, NBLK, 0, stream>>>(hist, bsum);
    scanB_kernel<<<1, 512, 0, stream>>>(bsum, ubase, pbase, N, E);
    scanC_kernel<<<NB, NBLK, 0, stream>>>(hist, ubase);
    passB_kernel<<<NBLK, 256, 0, stream>>>(src, dst, hist, ebuf, E);
    passC_kernel<<<NB, 256, 0, stream>>>(ebuf, ubase, pbase, rowptr, degs, dis, colidx, N);

    w1t_kernel<<<128, 256, 0, stream>>>(W1, W1T, (unsigned*)h1T, (unsigned*)h2sb, N);

    gemm1_mfma_kernel<<<(N + 31) / 32, 256, 0, stream>>>(x, W1T, dis,
                                                         (unsigned short*)h1T, N);

    const int bps = (N + 15) / 16;   // blocks per slab
    aggall_kernel<<<4 * bps, 256, 0, stream>>>(rowptr, degs, colidx, h1T, aggT, N, bps);

    relu_gemm2_kernel<<<(N + 3) / 4, 256, 0, stream>>>(aggT, dis, b1, W2, h2sb, N);

    layer2_kernel<<<((size_t)N * 8 + 255) / 256, 256, 0, stream>>>(rowptr, degs, colidx, h2sb, dis, b2, out, N);
}